// Round 2
// baseline (1017.945 us; speedup 1.0000x reference)
//
#include <hip/hip_runtime.h>

typedef unsigned short u16;
using short8_t  = __attribute__((ext_vector_type(8)))  short;
using float16_t = __attribute__((ext_vector_type(16))) float;

#define NKT 260          // K-steps of 16: K = 64*64 + 64 = 4160

__device__ __forceinline__ float bf2f(u16 b) { return __uint_as_float(((unsigned)b) << 16); }
__device__ __forceinline__ u16 f2bf(float f) {
  unsigned u = __float_as_uint(f);
  return (u16)((u + 0x7fffu + ((u >> 16) & 1u)) >> 16);   // RNE
}

union U8 { short8_t s; uint4 v; unsigned u[4]; };

// z = (h * x) rounded to bf16, 8 elements (round-half-up; ties are rare, bias negligible)
__device__ __forceinline__ short8_t scale8(short8_t x8, float hs) {
  U8 in, out;
  in.s = x8;
  #pragma unroll
  for (int p = 0; p < 4; ++p) {
    unsigned w = in.u[p];
    float lo = __uint_as_float(w << 16) * hs;
    float hi = __uint_as_float(w & 0xffff0000u) * hs;
    unsigned lor = (__float_as_uint(lo) + 0x8000u) >> 16;
    unsigned hir = (__float_as_uint(hi) + 0x8000u) & 0xffff0000u;
    out.u[p] = hir | lor;
  }
  return out.s;
}

// ---------------- relu(X @ W + b): f32 in, bf16 out. W is [IN,64] f32 ----------------
template<int IN>
__global__ __launch_bounds__(256) void affine_relu_kernel(
    const float* __restrict__ Xin, const float* __restrict__ W, const float* __restrict__ Bv,
    u16* __restrict__ Xout, int N)
{
  int gid = blockIdx.x * 256 + threadIdx.x;
  int n = gid >> 6, o = gid & 63;
  if (n >= N) return;
  float acc = Bv[o];
  #pragma unroll
  for (int i = 0; i < IN; ++i)
    acc = fmaf(Xin[n * IN + i], W[i * 64 + o], acc);
  Xout[gid] = f2bf(fmaxf(acc, 0.f));
}

// ---------------- pack B_ext [4160,64] (f32 w2/b2) into bf16 MFMA per-lane fragment order ----
// entry = (kt*2+nt)*64 + lane; element j = B_ext[kt*16 + (lane>>5)*8 + j][nt*32 + (lane&31)]
// B_ext[k,o]: k<4096 -> w2[(k>>6)*4096 + (k&63)*64 + o];  k>=4096 -> b2[(k-4096)*64 + o]
__global__ __launch_bounds__(256) void bpack_kernel(
    const float* __restrict__ w2, const float* __restrict__ b2, u16* __restrict__ Bp)
{
  int gid = blockIdx.x * 256 + threadIdx.x;
  if (gid >= NKT * 128) return;
  int lane = gid & 63;
  int nt = (gid >> 6) & 1;
  int kt = gid >> 7;
  int o = nt * 32 + (lane & 31);
  int kbase = kt * 16 + (lane >> 5) * 8;
  u16 vals[8];
  #pragma unroll
  for (int j = 0; j < 8; ++j) {
    int k = kbase + j;
    vals[j] = f2bf((k < 4096) ? w2[(k >> 6) * 4096 + (k & 63) * 64 + o]
                              : b2[(k - 4096) * 64 + o]);
  }
  uint4 pack;
  pack.x = (unsigned)vals[0] | ((unsigned)vals[1] << 16);
  pack.y = (unsigned)vals[2] | ((unsigned)vals[3] << 16);
  pack.z = (unsigned)vals[4] | ((unsigned)vals[5] << 16);
  pack.w = (unsigned)vals[6] | ((unsigned)vals[7] << 16);
  *(uint4*)(Bp + (size_t)gid * 8) = pack;
}

// ---------------- in-degree histogram + reciprocal ----------------
__global__ __launch_bounds__(256) void hist_kernel(const int* __restrict__ eidx, int* __restrict__ cnt, int E)
{
  int e = blockIdx.x * 256 + threadIdx.x;
  if (e < E) atomicAdd(cnt + eidx[E + e], 1);
}
__global__ __launch_bounds__(256) void rcnt_kernel(const int* __restrict__ cnt, float* __restrict__ rcnt, int N)
{
  int n = blockIdx.x * 256 + threadIdx.x;
  if (n < N) rcnt[n] = 1.0f / fmaxf((float)cnt[n], 1.0f);
}

// ---------------- msg = [h (x) x, x] @ B_ext, scatter-add to agg ----------------
// grid (ceil(E/128), 2): 128 edges/block, split-K (half 0: kt 0..127, half 1: 128..259)
// 4 waves; wave w owns edges [w*32, w*32+32), full 64 output cols (2x mfma_32x32x16 acc)
__global__ __launch_bounds__(256) void msg_gemm_kernel(
    const u16* __restrict__ X, const u16* __restrict__ Hh,
    const u16* __restrict__ Bp, const int* __restrict__ eidx,
    float* __restrict__ agg, int E)
{
  __shared__ __align__(16) u16 x_lds[128 * 72];   // padded stride 72 (16B-aligned rows)
  __shared__ __align__(16) u16 h_lds[128 * 72];
  __shared__ int tgt_lds[128];

  const int t = threadIdx.x;
  const int e0 = blockIdx.x * 128;

  { // stage h: contiguous rows, fully coalesced
    const uint4* hsrc = (const uint4*)(Hh + (size_t)e0 * 64);
    const int rows = E - e0;
    #pragma unroll
    for (int c = 0; c < 4; ++c) {
      int idx = t + c * 256;               // uint4 index 0..1023 (8 u16 each)
      int row = idx >> 3;
      uint4 val = make_uint4(0, 0, 0, 0);
      if (row < rows) val = hsrc[idx];
      *(uint4*)(h_lds + row * 72 + (idx & 7) * 8) = val;
    }
    // stage x: gather by src, 2 threads/row, 64 B each
    int r = t >> 1, half = t & 1;
    int e = e0 + r;
    uint4 v0 = make_uint4(0,0,0,0), v1 = v0, v2 = v0, v3 = v0;
    if (e < E) {
      int s = eidx[e];
      const uint4* xp = (const uint4*)(X + (size_t)s * 64 + half * 32);
      v0 = xp[0]; v1 = xp[1]; v2 = xp[2]; v3 = xp[3];
    }
    uint4* xd = (uint4*)(x_lds + r * 72 + half * 32);
    xd[0] = v0; xd[1] = v1; xd[2] = v2; xd[3] = v3;
    if (t < 128) tgt_lds[t] = (e0 + t < E) ? eidx[E + e0 + t] : -1;
  }
  __syncthreads();

  const int lane = t & 63;
  const int w = t >> 6;
  const int ml = lane & 31;
  const int m = w * 32 + ml;
  const int q = lane >> 5;
  const u16* xrow = x_lds + m * 72;
  const u16* hrow = h_lds + m * 72;

  float16_t acc0, acc1;
  #pragma unroll
  for (int i = 0; i < 16; ++i) { acc0[i] = 0.f; acc1[i] = 0.f; }

  const uint4* bbase = (const uint4*)Bp + lane;

  const int ktA = blockIdx.y ? 128 : 0;
  const int ktB = blockIdx.y ? 256 : 128;
  #pragma unroll 4
  for (int kt = ktA; kt < ktB; ++kt) {
    float hs = bf2f(hrow[kt >> 2]);                                   // h_e[kt>>2]
    short8_t x8 = *(const short8_t*)(xrow + ((kt & 3) << 4) + (q << 3)); // x_e[i0..i0+8)
    short8_t a = scale8(x8, hs);
    U8 b0, b1;
    b0.v = bbase[(kt * 2 + 0) * 64];
    b1.v = bbase[(kt * 2 + 1) * 64];
    acc0 = __builtin_amdgcn_mfma_f32_32x32x16_bf16(a, b0.s, acc0, 0, 0, 0);
    acc1 = __builtin_amdgcn_mfma_f32_32x32x16_bf16(a, b1.s, acc1, 0, 0, 0);
  }
  if (blockIdx.y) {  // b2 tail rows 4096..4159: A = x directly
    #pragma unroll
    for (int kt = 256; kt < 260; ++kt) {
      short8_t a = *(const short8_t*)(xrow + ((kt - 256) << 4) + (q << 3));
      U8 b0, b1;
      b0.v = bbase[(kt * 2 + 0) * 64];
      b1.v = bbase[(kt * 2 + 1) * 64];
      acc0 = __builtin_amdgcn_mfma_f32_32x32x16_bf16(a, b0.s, acc0, 0, 0, 0);
      acc1 = __builtin_amdgcn_mfma_f32_32x32x16_bf16(a, b1.s, acc1, 0, 0, 0);
    }
  }

  // epilogue: C/D layout col=lane&31, row=(reg&3)+8*(reg>>2)+4*(lane>>5)
  #pragma unroll
  for (int reg = 0; reg < 16; ++reg) {
    int row = (reg & 3) + 8 * (reg >> 2) + 4 * q;
    int tnode = tgt_lds[w * 32 + row];
    if (tnode >= 0) {
      atomicAdd(agg + (size_t)tnode * 64 + ml,      acc0[reg]);
      atomicAdd(agg + (size_t)tnode * 64 + 32 + ml, acc1[reg]);
    }
  }
}

// ---------------- x_new = relu(x @ root + agg*rcnt + bias) ----------------
__global__ __launch_bounds__(256) void update_kernel(
    const u16* __restrict__ Xin, const float* __restrict__ agg, const float* __restrict__ rcnt,
    const float* __restrict__ root, const float* __restrict__ bias, u16* __restrict__ Xout, int N)
{
  __shared__ float root_s[64 * 64];
  __shared__ float xrow_s[4][64];
  int t = threadIdx.x;
  for (int idx = t; idx < 4096; idx += 256) root_s[idx] = root[idx];
  int ln = t >> 6, o = t & 63;
  int n = blockIdx.x * 4 + ln;
  if (n < N) xrow_s[ln][o] = bf2f(Xin[n * 64 + o]);
  __syncthreads();
  if (n >= N) return;
  float acc = bias[o] + agg[(size_t)n * 64 + o] * rcnt[n];
  #pragma unroll
  for (int i = 0; i < 64; ++i)
    acc = fmaf(xrow_s[ln][i], root_s[i * 64 + o], acc);
  Xout[n * 64 + o] = f2bf(fmaxf(acc, 0.f));
}

// ---------------- column-sum pool: out64[o] += sum_n X[n,o] ----------------
__global__ __launch_bounds__(256) void pool_kernel(const u16* __restrict__ X, float* __restrict__ out64, int N)
{
  __shared__ float red[4][64];
  int t = threadIdx.x, o = t & 63, rg = t >> 6;
  float s = 0.f;
  for (int nn = rg; nn < 1024; nn += 4) {
    int n = blockIdx.x * 1024 + nn;
    if (n < N) s += bf2f(X[n * 64 + o]);
  }
  red[rg][o] = s;
  __syncthreads();
  if (rg == 0) atomicAdd(out64 + o, red[0][o] + red[1][o] + red[2][o] + red[3][o]);
}

// ---------------- head MLP: [131] -> 384 -> 6x384 -> 1 (all f32) ----------------
__global__ __launch_bounds__(384) void head_kernel(
    const float* __restrict__ pg, const float* __restrict__ plg, const float* __restrict__ adduct,
    const float* __restrict__ bw, const float* __restrict__ bb,
    const float* __restrict__ l1w, const float* __restrict__ l1b,
    const float* __restrict__ l2w, const float* __restrict__ l2b,
    float* __restrict__ out)
{
  __shared__ float v[131];
  __shared__ float u[384];
  __shared__ float wred[6];
  int t = threadIdx.x;
  if (t < 131) v[t] = (t < 64) ? pg[t] : (t < 128 ? plg[t - 64] : adduct[t - 128]);
  __syncthreads();
  float a = bb[t];
  for (int i = 0; i < 131; ++i) a = fmaf(v[i], bw[i * 384 + t], a);
  u[t] = fmaxf(a, 0.f);
  __syncthreads();
  for (int L = 0; L < 6; ++L) {
    float b = l1b[t];
    #pragma unroll 4
    for (int i = 0; i < 384; ++i) b = fmaf(u[i], l1w[i * 384 + t], b);
    b = fmaxf(b, 0.f);
    __syncthreads();
    u[t] = b;
    __syncthreads();
  }
  float p = u[t] * l2w[t];
  #pragma unroll
  for (int off = 32; off > 0; off >>= 1) p += __shfl_down(p, off);
  if ((t & 63) == 0) wred[t >> 6] = p;
  __syncthreads();
  if (t == 0) {
    float s = l2b[0];
    #pragma unroll
    for (int i = 0; i < 6; ++i) s += wred[i];
    out[0] = s;
  }
}

// ---------------- host driver ----------------
template<int INX, int INE>
static void run_branch(const float* Xraw, const float* l0w, const float* l0b,
                       const int* eidx, const float* ea,
                       const float* w1, const float* b1, const float* w2, const float* b2,
                       const float* root, const float* bias,
                       int N, int E,
                       u16* xa, u16* xb, u16* hbuf, u16* bp,
                       float* agg, int* cnt, float* rcnt, float* pool,
                       hipStream_t stream)
{
  affine_relu_kernel<INX><<<(N * 64 + 255) / 256, 256, 0, stream>>>(Xraw, l0w, l0b, xa, N);
  affine_relu_kernel<INE><<<(E * 64 + 255) / 256, 256, 0, stream>>>(ea, w1, b1, hbuf, E);
  bpack_kernel<<<(NKT * 128 + 255) / 256, 256, 0, stream>>>(w2, b2, bp);
  hipMemsetAsync(cnt, 0, (size_t)N * 4, stream);
  hist_kernel<<<(E + 255) / 256, 256, 0, stream>>>(eidx, cnt, E);
  rcnt_kernel<<<(N + 255) / 256, 256, 0, stream>>>(cnt, rcnt, N);
  u16* xc = xa; u16* xn = xb;
  for (int it = 0; it < 3; ++it) {
    hipMemsetAsync(agg, 0, (size_t)N * 64 * 4, stream);
    msg_gemm_kernel<<<dim3((E + 127) / 128, 2), 256, 0, stream>>>(xc, hbuf, bp, eidx, agg, E);
    update_kernel<<<(N + 3) / 4, 256, 0, stream>>>(xc, agg, rcnt, root, bias, xn, N);
    u16* tmp = xc; xc = xn; xn = tmp;
  }
  hipMemsetAsync(pool, 0, 64 * 4, stream);
  pool_kernel<<<(N + 1023) / 1024, 256, 0, stream>>>(xc, pool, N);
}

extern "C" void kernel_launch(void* const* d_in, const int* in_sizes, int n_in,
                              void* d_out, int out_size, void* d_ws, size_t ws_size,
                              hipStream_t stream)
{
  const int NG = 30000, EG = 60000, NLG = 60000, ELG = 60000;

  const float* gx      = (const float*)d_in[0];
  const int*   g_ei    = (const int*)  d_in[1];
  const float* g_ea    = (const float*)d_in[2];
  const float* lgx     = (const float*)d_in[3];
  const int*   lg_ei   = (const int*)  d_in[4];
  const float* lg_ea   = (const float*)d_in[5];
  const float* adduct  = (const float*)d_in[6];
  const float* lin0_w  = (const float*)d_in[7];
  const float* lin0_b  = (const float*)d_in[8];
  const float* g_w1    = (const float*)d_in[9];
  const float* g_b1    = (const float*)d_in[10];
  const float* g_w2    = (const float*)d_in[11];
  const float* g_b2    = (const float*)d_in[12];
  const float* g_root  = (const float*)d_in[13];
  const float* g_bias  = (const float*)d_in[14];
  const float* l0lg_w  = (const float*)d_in[15];
  const float* l0lg_b  = (const float*)d_in[16];
  const float* lg_w1   = (const float*)d_in[17];
  const float* lg_b1   = (const float*)d_in[18];
  const float* lg_w2   = (const float*)d_in[19];
  const float* lg_b2   = (const float*)d_in[20];
  const float* lg_root = (const float*)d_in[21];
  const float* lg_bias = (const float*)d_in[22];
  const float* bott_w  = (const float*)d_in[23];
  const float* bott_b  = (const float*)d_in[24];
  const float* lin1_w  = (const float*)d_in[25];
  const float* lin1_b  = (const float*)d_in[26];
  const float* lin2_w  = (const float*)d_in[27];
  const float* lin2_b  = (const float*)d_in[28];

  char* p = (char*)d_ws;
  auto alloc = [&](size_t bytes) { char* r = p; p += (bytes + 255) & ~(size_t)255; return r; };
  // shared between the two sequential branches to minimize ws footprint (~40 MB)
  u16*   xa     = (u16*)  alloc((size_t)NLG * 64 * 2);
  u16*   xb     = (u16*)  alloc((size_t)NLG * 64 * 2);
  u16*   hbuf   = (u16*)  alloc((size_t)ELG * 64 * 2);
  u16*   bp     = (u16*)  alloc((size_t)NKT * 128 * 8 * 2);
  float* agg    = (float*)alloc((size_t)NLG * 64 * 4);
  int*   cnt    = (int*)  alloc((size_t)NLG * 4);
  float* rcnt   = (float*)alloc((size_t)NLG * 4);
  float* pool_g = (float*)alloc(64 * 4);
  float* pool_l = (float*)alloc(64 * 4);

  run_branch<20, 4>(gx, lin0_w, lin0_b, g_ei, g_ea, g_w1, g_b1, g_w2, g_b2, g_root, g_bias,
                    NG, EG, xa, xb, hbuf, bp, agg, cnt, rcnt, pool_g, stream);
  run_branch<5, 1>(lgx, l0lg_w, l0lg_b, lg_ei, lg_ea, lg_w1, lg_b1, lg_w2, lg_b2, lg_root, lg_bias,
                   NLG, ELG, xa, xb, hbuf, bp, agg, cnt, rcnt, pool_l, stream);

  head_kernel<<<1, 384, 0, stream>>>(pool_g, pool_l, adduct,
                                     bott_w, bott_b, lin1_w, lin1_b, lin2_w, lin2_b,
                                     (float*)d_out);
}